// Round 2
// baseline (127.039 us; speedup 1.0000x reference)
//
#include <hip/hip_runtime.h>
#include <math.h>

#define NT 32768
#define SCALEF 4.0f

// broadcast-readlane: value of v in lane l -> SGPR (uniform), feeds FMA src
__device__ __forceinline__ float rl(float v, int l) {
    return __int_as_float(__builtin_amdgcn_readlane(__float_as_int(v), l));
}

__device__ __forceinline__ float frame_val(const float* __restrict__ obs,
                                           const float* __restrict__ pred,
                                           int F, int d) {
    return (F < 9) ? obs[F * (NT * 2) + d] : pred[(F - 9) * (NT * 2) + d];
}

// 4 MACs: acc += h[l..l+3] * W.{x,y,z,w}, h broadcast via readlane
#define MAC4(acc, hv, l, W)                       \
    acc = fmaf(rl(hv, (l) + 0), W.x, acc);        \
    acc = fmaf(rl(hv, (l) + 1), W.y, acc);        \
    acc = fmaf(rl(hv, (l) + 2), W.z, acc);        \
    acc = fmaf(rl(hv, (l) + 3), W.w, acc);

__launch_bounds__(512, 2)
__global__ void lstm_disc_kernel(const float* __restrict__ observed,
                                 const float* __restrict__ prediction,
                                 const float* __restrict__ W_emb,
                                 const float* __restrict__ b_emb,
                                 const float* __restrict__ W_ih,
                                 const float* __restrict__ W_hh,
                                 const float* __restrict__ b_ih,
                                 const float* __restrict__ b_hh,
                                 const float* __restrict__ W1,
                                 const float* __restrict__ b1,
                                 const float* __restrict__ W2,
                                 const float* __restrict__ b2,
                                 const float* __restrict__ W3,
                                 const float* __restrict__ b3,
                                 float* __restrict__ out)
{
    const int tid  = (int)threadIdx.x;   // gate index j in [0,512)
    const int lane = tid & 63;

    __shared__ float xs[21][64];      // per-step input embedding vectors
    __shared__ float gx[21][512];     // h-independent gate pre-activations
    __shared__ float velx[21], vely[21], maskf[21];
    __shared__ float gact[512];       // activated gates of current step
    __shared__ float hbuf[128];
    __shared__ float mlp1[64];
    __shared__ float mlp2[32];

    // ---- issue weight loads FIRST (HBM latency overlapped by gx compute) ----
    // W_hh row of this gate: 128 floats = 32 float4 named registers A0..A15 (k<64), B0..B15 (k>=64)
    const float4* Wh = reinterpret_cast<const float4*>(W_hh + tid * 128);
    float4 A0  = Wh[0],  A1  = Wh[1],  A2  = Wh[2],  A3  = Wh[3];
    float4 A4  = Wh[4],  A5  = Wh[5],  A6  = Wh[6],  A7  = Wh[7];
    float4 A8  = Wh[8],  A9  = Wh[9],  A10 = Wh[10], A11 = Wh[11];
    float4 A12 = Wh[12], A13 = Wh[13], A14 = Wh[14], A15 = Wh[15];
    float4 B0  = Wh[16], B1  = Wh[17], B2  = Wh[18], B3  = Wh[19];
    float4 B4  = Wh[20], B5  = Wh[21], B6  = Wh[22], B7  = Wh[23];
    float4 B8  = Wh[24], B9  = Wh[25], B10 = Wh[26], B11 = Wh[27];
    float4 B12 = Wh[28], B13 = Wh[29], B14 = Wh[30], B15 = Wh[31];
    // W_ih row: 64 floats = 16 float4 named registers C0..C15
    const float4* Wi = reinterpret_cast<const float4*>(W_ih + tid * 64);
    float4 C0  = Wi[0],  C1  = Wi[1],  C2  = Wi[2],  C3  = Wi[3];
    float4 C4  = Wi[4],  C5  = Wi[5],  C6  = Wi[6],  C7  = Wi[7];
    float4 C8  = Wi[8],  C9  = Wi[9],  C10 = Wi[10], C11 = Wi[11];
    float4 C12 = Wi[12], C13 = Wi[13], C14 = Wi[14], C15 = Wi[15];
    const float bias = b_ih[tid] + b_hh[tid];

    // ---- (a) velocities + visibility masks for track 0 ----
    if (tid < 20) {
        float ax = frame_val(observed, prediction, tid,     0);
        float ay = frame_val(observed, prediction, tid,     1);
        float bx = frame_val(observed, prediction, tid + 1, 0);
        float by = frame_val(observed, prediction, tid + 1, 1);
        unsigned ua = __float_as_uint(ax) & 0x7fffffffu;
        unsigned ub = __float_as_uint(bx) & 0x7fffffffu;
        bool m = !((ua > 0x7f800000u) || (ub > 0x7f800000u));   // NaN-safe, fast-math-proof
        maskf[tid + 1] = m ? 1.0f : 0.0f;
        velx[tid + 1]  = m ? (bx - ax) * SCALEF : 0.0f;
        vely[tid + 1]  = m ? (by - ay) * SCALEF : 0.0f;
    }
    if (tid == 20) { maskf[0] = 1.0f; velx[0] = 0.0f; vely[0] = 0.0f; }
    __syncthreads();

    // ---- (b) x vectors: xs[0] = start tag one-hot, xs[1..20] = relu(vel*S @ W_emb^T + b) ++ [0,0]
    for (int idx = tid; idx < 21 * 64; idx += 512) {
        int s = idx >> 6, e = idx & 63;
        float v;
        if (s == 0)       v = (e == 62) ? 1.0f : 0.0f;
        else if (e < 62)  v = fmaxf(velx[s] * W_emb[2 * e] + vely[s] * W_emb[2 * e + 1] + b_emb[e], 0.0f);
        else              v = 0.0f;
        xs[s][e] = v;
    }
    __syncthreads();

    // uniform step mask bits
    unsigned mbits = 0;
    #pragma unroll
    for (int s = 0; s < 21; ++s) mbits |= (maskf[s] != 0.0f ? 1u : 0u) << s;

    // ---- (c) gx[s][j] = x_s . W_ih[j] + b_ih[j] + b_hh[j]  (h-independent)
    gx[0][tid] = bias + C15.z;                         // tag one-hot at position 62
    for (int s = 1; s < 21; ++s) {
        float xc = xs[s][lane];                        // lane-held column of x_s
        float a0 = bias, a1 = 0.0f;
        MAC4(a0, xc,  0, C0)  MAC4(a1, xc,  4, C1)
        MAC4(a0, xc,  8, C2)  MAC4(a1, xc, 12, C3)
        MAC4(a0, xc, 16, C4)  MAC4(a1, xc, 20, C5)
        MAC4(a0, xc, 24, C6)  MAC4(a1, xc, 28, C7)
        MAC4(a0, xc, 32, C8)  MAC4(a1, xc, 36, C9)
        MAC4(a0, xc, 40, C10) MAC4(a1, xc, 44, C11)
        MAC4(a0, xc, 48, C12) MAC4(a1, xc, 52, C13)
        MAC4(a0, xc, 56, C14)                          // e = 56..59
        a1 = fmaf(rl(xc, 60), C15.x, a1);              // e = 60
        a1 = fmaf(rl(xc, 61), C15.y, a1);              // e = 61; 62,63 are zero in x
        gx[s][tid] = a0 + a1;
    }

    // ---- (d) serial recurrence: W_hh register-resident, readlane h-broadcast ----
    float hlo = 0.0f, hhi = 0.0f, creg = 0.0f;          // h[lane], h[64+lane]; c[tid] for tid<128
    const int gtype = tid >> 7;                         // 0=i 1=f 2=g 3=o

    for (int s = 0; s < 21; ++s) {
        if (mbits & (1u << s)) {                        // uniform branch
            float acc0 = gx[s][tid], acc1 = 0.0f;
            MAC4(acc0, hlo,  0, A0)  MAC4(acc1, hlo,  4, A1)
            MAC4(acc0, hlo,  8, A2)  MAC4(acc1, hlo, 12, A3)
            MAC4(acc0, hlo, 16, A4)  MAC4(acc1, hlo, 20, A5)
            MAC4(acc0, hlo, 24, A6)  MAC4(acc1, hlo, 28, A7)
            MAC4(acc0, hlo, 32, A8)  MAC4(acc1, hlo, 36, A9)
            MAC4(acc0, hlo, 40, A10) MAC4(acc1, hlo, 44, A11)
            MAC4(acc0, hlo, 48, A12) MAC4(acc1, hlo, 52, A13)
            MAC4(acc0, hlo, 56, A14) MAC4(acc1, hlo, 60, A15)
            MAC4(acc0, hhi,  0, B0)  MAC4(acc1, hhi,  4, B1)
            MAC4(acc0, hhi,  8, B2)  MAC4(acc1, hhi, 12, B3)
            MAC4(acc0, hhi, 16, B4)  MAC4(acc1, hhi, 20, B5)
            MAC4(acc0, hhi, 24, B6)  MAC4(acc1, hhi, 28, B7)
            MAC4(acc0, hhi, 32, B8)  MAC4(acc1, hhi, 36, B9)
            MAC4(acc0, hhi, 40, B10) MAC4(acc1, hhi, 44, B11)
            MAC4(acc0, hhi, 48, B12) MAC4(acc1, hhi, 52, B13)
            MAC4(acc0, hhi, 56, B14) MAC4(acc1, hhi, 60, B15)
            float acc = acc0 + acc1;
            float a = (gtype == 2) ? tanhf(acc) : 1.0f / (1.0f + expf(-acc));
            gact[tid] = a;
            __syncthreads();
            if (tid < 128) {
                float gi = gact[tid], gf = gact[128 + tid], gg = gact[256 + tid], go = gact[384 + tid];
                creg = gf * creg + gi * gg;
                hbuf[tid] = go * tanhf(creg);
            }
            __syncthreads();
            hlo = hbuf[lane];
            hhi = hbuf[64 + lane];
        }
    }

    // ---- (e) classifier MLP on h (track 0) ----
    if (tid < 64) {
        float a = b1[tid];
        #pragma unroll
        for (int k = 0; k < 128; ++k) a += W1[tid * 128 + k] * hbuf[k];
        mlp1[tid] = fmaxf(a, 0.0f);
    }
    __syncthreads();
    if (tid < 32) {
        float a = b2[tid];
        #pragma unroll
        for (int k = 0; k < 64; ++k) a += W2[tid * 64 + k] * mlp1[k];
        mlp2[tid] = fmaxf(a, 0.0f);
    }
    __syncthreads();
    if (tid == 0) {
        float a = b3[0];
        #pragma unroll
        for (int k = 0; k < 32; ++k) a += W3[k] * mlp2[k];
        out[0] = fmaxf(a, 0.0f);
    }
}

extern "C" void kernel_launch(void* const* d_in, const int* in_sizes, int n_in,
                              void* d_out, int out_size, void* d_ws, size_t ws_size,
                              hipStream_t stream) {
    lstm_disc_kernel<<<1, 512, 0, stream>>>(
        (const float*)d_in[0],  (const float*)d_in[1],
        (const float*)d_in[2],  (const float*)d_in[3],
        (const float*)d_in[4],  (const float*)d_in[5],
        (const float*)d_in[6],  (const float*)d_in[7],
        (const float*)d_in[8],  (const float*)d_in[9],
        (const float*)d_in[10], (const float*)d_in[11],
        (const float*)d_in[12], (const float*)d_in[13],
        (float*)d_out);
}

// Round 3
// 124.399 us; speedup vs baseline: 1.0212x; 1.0212x over previous
//
#include <hip/hip_runtime.h>
#include <math.h>

#define NT 32768
#define SCALEF 4.0f

// broadcast-readlane: value of v in lane l -> SGPR (wave-uniform), feeds FMA src
__device__ __forceinline__ float rl(float v, int l) {
    return __int_as_float(__builtin_amdgcn_readlane(__float_as_int(v), l));
}

// fast activations: v_exp_f32 + v_rcp_f32 (~1-2 ulp), monotone & saturating
__device__ __forceinline__ float sigf(float x) {
    return __builtin_amdgcn_rcpf(1.0f + __expf(-x));
}
__device__ __forceinline__ float tanhfast(float x) {
    return 1.0f - 2.0f * __builtin_amdgcn_rcpf(1.0f + __expf(2.0f * x));
}

__device__ __forceinline__ float frame_val(const float* __restrict__ obs,
                                           const float* __restrict__ pred,
                                           int F, int d) {
    return (F < 9) ? obs[F * (NT * 2) + d] : pred[(F - 9) * (NT * 2) + d];
}

// 4 MACs: acc += h[l..l+3] * W.{x,y,z,w}, h broadcast via readlane
#define MAC4(acc, hv, l, W)                       \
    acc = fmaf(rl(hv, (l) + 0), W.x, acc);        \
    acc = fmaf(rl(hv, (l) + 1), W.y, acc);        \
    acc = fmaf(rl(hv, (l) + 2), W.z, acc);        \
    acc = fmaf(rl(hv, (l) + 3), W.w, acc);

// block = 512 (8 waves, one CU). Second arg 1 => 2 waves/SIMD => 256-VGPR cap:
// W_hh row (32 float4) + W_ih row (16 float4) stay register-resident (no spill).
__launch_bounds__(512, 1)
__global__ void lstm_disc_kernel(const float* __restrict__ observed,
                                 const float* __restrict__ prediction,
                                 const float* __restrict__ W_emb,
                                 const float* __restrict__ b_emb,
                                 const float* __restrict__ W_ih,
                                 const float* __restrict__ W_hh,
                                 const float* __restrict__ b_ih,
                                 const float* __restrict__ b_hh,
                                 const float* __restrict__ W1,
                                 const float* __restrict__ b1,
                                 const float* __restrict__ W2,
                                 const float* __restrict__ b2,
                                 const float* __restrict__ W3,
                                 const float* __restrict__ b3,
                                 float* __restrict__ out)
{
    const int tid  = (int)threadIdx.x;   // gate index j in [0,512)
    const int lane = tid & 63;

    __shared__ float xs[21][64];        // per-step input embedding vectors
    __shared__ float gxl[21 * 512];     // h-independent gate pre-activations
    __shared__ float velx[21], vely[21], maskf[21];
    __shared__ float gact[512];         // activated gates of current step
    __shared__ float hbuf[128];
    __shared__ float mlp1[64];
    __shared__ float mlp2[32];

    // ---- issue weight loads first; W_ih BEFORE W_hh so using C regs in the gx
    // phase doesn't force the W_hh loads to drain (vmcnt is ordered).
    const float4* Wi = reinterpret_cast<const float4*>(W_ih + tid * 64);
    float4 C0  = Wi[0],  C1  = Wi[1],  C2  = Wi[2],  C3  = Wi[3];
    float4 C4  = Wi[4],  C5  = Wi[5],  C6  = Wi[6],  C7  = Wi[7];
    float4 C8  = Wi[8],  C9  = Wi[9],  C10 = Wi[10], C11 = Wi[11];
    float4 C12 = Wi[12], C13 = Wi[13], C14 = Wi[14], C15 = Wi[15];
    const float bias = b_ih[tid] + b_hh[tid];

    const float4* Wh = reinterpret_cast<const float4*>(W_hh + tid * 128);
    float4 A0  = Wh[0],  A1  = Wh[1],  A2  = Wh[2],  A3  = Wh[3];
    float4 A4  = Wh[4],  A5  = Wh[5],  A6  = Wh[6],  A7  = Wh[7];
    float4 A8  = Wh[8],  A9  = Wh[9],  A10 = Wh[10], A11 = Wh[11];
    float4 A12 = Wh[12], A13 = Wh[13], A14 = Wh[14], A15 = Wh[15];
    float4 B0  = Wh[16], B1  = Wh[17], B2  = Wh[18], B3  = Wh[19];
    float4 B4  = Wh[20], B5  = Wh[21], B6  = Wh[22], B7  = Wh[23];
    float4 B8  = Wh[24], B9  = Wh[25], B10 = Wh[26], B11 = Wh[27];
    float4 B12 = Wh[28], B13 = Wh[29], B14 = Wh[30], B15 = Wh[31];

    // ---- (a) velocities + visibility masks for track 0 ----
    if (tid < 20) {
        float ax = frame_val(observed, prediction, tid,     0);
        float ay = frame_val(observed, prediction, tid,     1);
        float bx = frame_val(observed, prediction, tid + 1, 0);
        float by = frame_val(observed, prediction, tid + 1, 1);
        unsigned ua = __float_as_uint(ax) & 0x7fffffffu;
        unsigned ub = __float_as_uint(bx) & 0x7fffffffu;
        bool m = !((ua > 0x7f800000u) || (ub > 0x7f800000u));   // NaN-safe
        maskf[tid + 1] = m ? 1.0f : 0.0f;
        velx[tid + 1]  = m ? (bx - ax) * SCALEF : 0.0f;
        vely[tid + 1]  = m ? (by - ay) * SCALEF : 0.0f;
    }
    if (tid == 20) { maskf[0] = 1.0f; velx[0] = 0.0f; vely[0] = 0.0f; }
    __syncthreads();

    // ---- (b) x vectors: xs[0] = start tag one-hot, xs[1..20] = relu(vel@W^T+b) ++ [0,0]
    for (int idx = tid; idx < 21 * 64; idx += 512) {
        int s = idx >> 6, e = idx & 63;
        float v;
        if (s == 0)       v = (e == 62) ? 1.0f : 0.0f;
        else if (e < 62)  v = fmaxf(velx[s] * W_emb[2 * e] + vely[s] * W_emb[2 * e + 1] + b_emb[e], 0.0f);
        else              v = 0.0f;
        xs[s][e] = v;
    }
    __syncthreads();

    // uniform step mask bits
    unsigned mbits = 0;
    #pragma unroll
    for (int s = 0; s < 21; ++s) mbits |= (maskf[s] != 0.0f ? 1u : 0u) << s;

    // ---- (c) gx[s][j] = x_s . W_ih[j] + bias  (h-independent, thread-own values)
    gxl[tid] = bias + C15.z;                           // s=0: tag one-hot at e=62
    float xc = xs[1][lane];                            // rotate: prefetch next step's x
    for (int s = 1; s < 21; ++s) {
        float xcn = (s < 20) ? xs[s + 1][lane] : 0.0f; // LDS latency hidden by dot below
        float a0 = bias, a1 = 0.0f;
        MAC4(a0, xc,  0, C0)  MAC4(a1, xc,  4, C1)
        MAC4(a0, xc,  8, C2)  MAC4(a1, xc, 12, C3)
        MAC4(a0, xc, 16, C4)  MAC4(a1, xc, 20, C5)
        MAC4(a0, xc, 24, C6)  MAC4(a1, xc, 28, C7)
        MAC4(a0, xc, 32, C8)  MAC4(a1, xc, 36, C9)
        MAC4(a0, xc, 40, C10) MAC4(a1, xc, 44, C11)
        MAC4(a0, xc, 48, C12) MAC4(a1, xc, 52, C13)
        MAC4(a0, xc, 56, C14)                          // e = 56..59
        a1 = fmaf(rl(xc, 60), C15.x, a1);              // e = 60
        a1 = fmaf(rl(xc, 61), C15.y, a1);              // e = 61; x[62..63] == 0
        gxl[s * 512 + tid] = a0 + a1;
        xc = xcn;
    }

    // ---- (d) serial recurrence: W_hh register-resident, readlane h-broadcast ----
    float hlo = 0.0f, hhi = 0.0f, creg = 0.0f;          // h[lane], h[64+lane]; c[tid] for tid<128
    const int gtype = tid >> 7;                         // 0=i 1=f 2=g 3=o

    for (int s = 0; s < 21; ++s) {
        if (mbits & (1u << s)) {                        // uniform branch
            float gxv = gxl[s * 512 + tid];             // thread-own; consumed at dot END
            float acc0 = 0.0f, acc1 = 0.0f;
            MAC4(acc0, hlo,  0, A0)  MAC4(acc1, hlo,  4, A1)
            MAC4(acc0, hlo,  8, A2)  MAC4(acc1, hlo, 12, A3)
            MAC4(acc0, hlo, 16, A4)  MAC4(acc1, hlo, 20, A5)
            MAC4(acc0, hlo, 24, A6)  MAC4(acc1, hlo, 28, A7)
            MAC4(acc0, hlo, 32, A8)  MAC4(acc1, hlo, 36, A9)
            MAC4(acc0, hlo, 40, A10) MAC4(acc1, hlo, 44, A11)
            MAC4(acc0, hlo, 48, A12) MAC4(acc1, hlo, 52, A13)
            MAC4(acc0, hlo, 56, A14) MAC4(acc1, hlo, 60, A15)
            MAC4(acc0, hhi,  0, B0)  MAC4(acc1, hhi,  4, B1)
            MAC4(acc0, hhi,  8, B2)  MAC4(acc1, hhi, 12, B3)
            MAC4(acc0, hhi, 16, B4)  MAC4(acc1, hhi, 20, B5)
            MAC4(acc0, hhi, 24, B6)  MAC4(acc1, hhi, 28, B7)
            MAC4(acc0, hhi, 32, B8)  MAC4(acc1, hhi, 36, B9)
            MAC4(acc0, hhi, 40, B10) MAC4(acc1, hhi, 44, B11)
            MAC4(acc0, hhi, 48, B12) MAC4(acc1, hhi, 52, B13)
            MAC4(acc0, hhi, 56, B14) MAC4(acc1, hhi, 60, B15)
            float acc = acc0 + acc1 + gxv;
            float a = (gtype == 2) ? tanhfast(acc) : sigf(acc);
            gact[tid] = a;
            __syncthreads();
            if (tid < 128) {
                float gi = gact[tid], gf = gact[128 + tid], gg = gact[256 + tid], go = gact[384 + tid];
                creg = gf * creg + gi * gg;
                hbuf[tid] = go * tanhfast(creg);
            }
            __syncthreads();
            hlo = hbuf[lane];
            hhi = hbuf[64 + lane];
        }
    }

    // ---- (e) classifier MLP on h (track 0), float4-vectorized ----
    if (tid < 64) {
        const float4* W1r = reinterpret_cast<const float4*>(W1 + tid * 128);
        float a = b1[tid];
        #pragma unroll
        for (int q = 0; q < 32; ++q) {
            float4 w = W1r[q];
            a = fmaf(w.x, hbuf[4*q], a);   a = fmaf(w.y, hbuf[4*q+1], a);
            a = fmaf(w.z, hbuf[4*q+2], a); a = fmaf(w.w, hbuf[4*q+3], a);
        }
        mlp1[tid] = fmaxf(a, 0.0f);
    }
    __syncthreads();
    if (tid < 32) {
        const float4* W2r = reinterpret_cast<const float4*>(W2 + tid * 64);
        float a = b2[tid];
        #pragma unroll
        for (int q = 0; q < 16; ++q) {
            float4 w = W2r[q];
            a = fmaf(w.x, mlp1[4*q], a);   a = fmaf(w.y, mlp1[4*q+1], a);
            a = fmaf(w.z, mlp1[4*q+2], a); a = fmaf(w.w, mlp1[4*q+3], a);
        }
        mlp2[tid] = fmaxf(a, 0.0f);
    }
    __syncthreads();
    if (tid == 0) {
        float a = b3[0];
        #pragma unroll
        for (int k = 0; k < 32; ++k) a += W3[k] * mlp2[k];
        out[0] = fmaxf(a, 0.0f);
    }
}

extern "C" void kernel_launch(void* const* d_in, const int* in_sizes, int n_in,
                              void* d_out, int out_size, void* d_ws, size_t ws_size,
                              hipStream_t stream) {
    lstm_disc_kernel<<<1, 512, 0, stream>>>(
        (const float*)d_in[0],  (const float*)d_in[1],
        (const float*)d_in[2],  (const float*)d_in[3],
        (const float*)d_in[4],  (const float*)d_in[5],
        (const float*)d_in[6],  (const float*)d_in[7],
        (const float*)d_in[8],  (const float*)d_in[9],
        (const float*)d_in[10], (const float*)d_in[11],
        (const float*)d_in[12], (const float*)d_in[13],
        (float*)d_out);
}

// Round 4
// 122.623 us; speedup vs baseline: 1.0360x; 1.0145x over previous
//
#include <hip/hip_runtime.h>
#include <math.h>

#define NT 32768
#define SCALEF 4.0f

// broadcast-readlane: value of v in lane l -> SGPR (wave-uniform), feeds FMA src
__device__ __forceinline__ float rl(float v, int l) {
    return __int_as_float(__builtin_amdgcn_readlane(__float_as_int(v), l));
}

// fast activations: v_exp_f32 + v_rcp_f32 (~1-2 ulp), monotone & saturating
__device__ __forceinline__ float sigf(float x) {
    return __builtin_amdgcn_rcpf(1.0f + __expf(-x));
}
__device__ __forceinline__ float tanhfast(float x) {
    return 1.0f - 2.0f * __builtin_amdgcn_rcpf(1.0f + __expf(2.0f * x));
}

__device__ __forceinline__ float frame_val(const float* __restrict__ obs,
                                           const float* __restrict__ pred,
                                           int F, int d) {
    return (F < 9) ? obs[F * (NT * 2) + d] : pred[(F - 9) * (NT * 2) + d];
}

// 4 MACs: acc += h[l..l+3] * W.{x,y,z,w}, h broadcast via readlane
#define MAC4(acc, hv, l, W)                       \
    acc = fmaf(rl(hv, (l) + 0), W.x, acc);        \
    acc = fmaf(rl(hv, (l) + 1), W.y, acc);        \
    acc = fmaf(rl(hv, (l) + 2), W.z, acc);        \
    acc = fmaf(rl(hv, (l) + 3), W.w, acc);

// 1024 threads = 16 waves = 4 waves/SIMD -> 128-VGPR budget, which our
// per-thread footprint (24 float4 weights + ~20 temps ~ 118 regs) fits.
// Thread t: gate j = t&511, half p = t>>9 (k-range [64p,64p+64) of W_hh,
// e-range [32p,32p+32) of W_ih). No register-allocator fight, no spill.
__launch_bounds__(1024, 4)
__global__ void lstm_disc_kernel(const float* __restrict__ observed,
                                 const float* __restrict__ prediction,
                                 const float* __restrict__ W_emb,
                                 const float* __restrict__ b_emb,
                                 const float* __restrict__ W_ih,
                                 const float* __restrict__ W_hh,
                                 const float* __restrict__ b_ih,
                                 const float* __restrict__ b_hh,
                                 const float* __restrict__ W1,
                                 const float* __restrict__ b1,
                                 const float* __restrict__ W2,
                                 const float* __restrict__ b2,
                                 const float* __restrict__ W3,
                                 const float* __restrict__ b3,
                                 float* __restrict__ out)
{
    const int tid  = (int)threadIdx.x;   // 0..1023
    const int lane = tid & 63;
    const int j    = tid & 511;          // gate index
    const int p    = tid >> 9;           // half index (wave-uniform)

    __shared__ float xs[21][64];         // per-step input embedding vectors
    __shared__ float gx0[21 * 512];      // h-independent gate pre-activations, half 0 (+bias)
    __shared__ float gx1[21 * 512];      // half 1
    __shared__ float ppart[1024];        // per-step W_hh dot partials
    __shared__ float gact[512];          // activated gates of current step
    __shared__ float hbuf[128];
    __shared__ float velx[21], vely[21], maskf[21];
    __shared__ float mlp1[64];
    __shared__ float mlp2[32];

    // ---- weight loads first (W_ih before W_hh: vmcnt is ordered, so waiting
    // on the C regs in the gx phase leaves the W_hh loads in flight).
    const float4* Wi = reinterpret_cast<const float4*>(W_ih + j * 64 + 32 * p);
    float4 C0 = Wi[0], C1 = Wi[1], C2 = Wi[2], C3 = Wi[3];
    float4 C4 = Wi[4], C5 = Wi[5], C6 = Wi[6], C7 = Wi[7];
    const float bias = b_ih[j] + b_hh[j];

    const float4* Wh = reinterpret_cast<const float4*>(W_hh + j * 128 + 64 * p);
    float4 D0  = Wh[0],  D1  = Wh[1],  D2  = Wh[2],  D3  = Wh[3];
    float4 D4  = Wh[4],  D5  = Wh[5],  D6  = Wh[6],  D7  = Wh[7];
    float4 D8  = Wh[8],  D9  = Wh[9],  D10 = Wh[10], D11 = Wh[11];
    float4 D12 = Wh[12], D13 = Wh[13], D14 = Wh[14], D15 = Wh[15];

    // ---- (a) velocities + visibility masks for track 0 ----
    if (tid < 20) {
        float ax = frame_val(observed, prediction, tid,     0);
        float ay = frame_val(observed, prediction, tid,     1);
        float bx = frame_val(observed, prediction, tid + 1, 0);
        float by = frame_val(observed, prediction, tid + 1, 1);
        unsigned ua = __float_as_uint(ax) & 0x7fffffffu;
        unsigned ub = __float_as_uint(bx) & 0x7fffffffu;
        bool m = !((ua > 0x7f800000u) || (ub > 0x7f800000u));   // NaN-safe
        maskf[tid + 1] = m ? 1.0f : 0.0f;
        velx[tid + 1]  = m ? (bx - ax) * SCALEF : 0.0f;
        vely[tid + 1]  = m ? (by - ay) * SCALEF : 0.0f;
    }
    if (tid == 20) { maskf[0] = 1.0f; velx[0] = 0.0f; vely[0] = 0.0f; }
    __syncthreads();

    // ---- (b) x vectors: xs[1..20] = relu(vel*S @ W_emb^T + b) ++ [0,0]
    for (int idx = tid; idx < 21 * 64; idx += 1024) {
        int s = idx >> 6, e = idx & 63;
        float v;
        if (s == 0)       v = (e == 62) ? 1.0f : 0.0f;   // start tag (unused; handled analytically)
        else if (e < 62)  v = fmaxf(velx[s] * W_emb[2 * e] + vely[s] * W_emb[2 * e + 1] + b_emb[e], 0.0f);
        else              v = 0.0f;
        xs[s][e] = v;
    }
    __syncthreads();

    // uniform step mask bits
    unsigned mbits = 0;
    #pragma unroll
    for (int s = 0; s < 21; ++s) mbits |= (maskf[s] != 0.0f ? 1u : 0u) << s;

    // ---- (c) gx half-partials: gx0[s][j] = bias + x_s[0:32).Wih_row, gx1[s][j] = x_s[32:62).Wih_row
    float* gdst = (p == 0) ? gx0 : gx1;
    const float basev = (p == 0) ? bias : 0.0f;
    // s = 0: tag one-hot at e=62 -> half 1 contributes C7.z, half 0 the bias
    gdst[j] = (p == 0) ? bias : C7.z;
    // lanes hold x duplicated: lane l -> x[32p + (l&31)]; rl(xcs,k) k<32 = x[32p+k]
    float xcs = xs[1][32 * p + (lane & 31)];
    for (int s = 1; s < 21; ++s) {
        float xcn = (s < 20) ? xs[s + 1][32 * p + (lane & 31)] : 0.0f;
        float a0 = basev, a1 = 0.0f;
        MAC4(a0, xcs,  0, C0) MAC4(a1, xcs,  4, C1)
        MAC4(a0, xcs,  8, C2) MAC4(a1, xcs, 12, C3)
        MAC4(a0, xcs, 16, C4) MAC4(a1, xcs, 20, C5)
        MAC4(a0, xcs, 24, C6) MAC4(a1, xcs, 28, C7)   // x[62..63]==0 for s>=1
        gdst[s * 512 + j] = a0 + a1;
        xcs = xcn;
    }
    __syncthreads();

    // ---- (d) serial recurrence ----
    float hseg = 0.0f;                  // h[64p + lane]
    float creg = 0.0f;                  // c[tid], valid for tid<128 (those have p==0)
    const int gtype = j >> 7;           // 0=i 1=f 2=g 3=o

    for (int s = 0; s < 21; ++s) {
        if (mbits & (1u << s)) {        // uniform branch
            float acc0 = 0.0f, acc1 = 0.0f;
            MAC4(acc0, hseg,  0, D0)  MAC4(acc1, hseg,  4, D1)
            MAC4(acc0, hseg,  8, D2)  MAC4(acc1, hseg, 12, D3)
            MAC4(acc0, hseg, 16, D4)  MAC4(acc1, hseg, 20, D5)
            MAC4(acc0, hseg, 24, D6)  MAC4(acc1, hseg, 28, D7)
            MAC4(acc0, hseg, 32, D8)  MAC4(acc1, hseg, 36, D9)
            MAC4(acc0, hseg, 40, D10) MAC4(acc1, hseg, 44, D11)
            MAC4(acc0, hseg, 48, D12) MAC4(acc1, hseg, 52, D13)
            MAC4(acc0, hseg, 56, D14) MAC4(acc1, hseg, 60, D15)
            ppart[tid] = acc0 + acc1;
            __syncthreads();
            if (tid < 512) {
                float acc = ppart[j] + ppart[512 + j] + gx0[s * 512 + j] + gx1[s * 512 + j];
                gact[j] = (gtype == 2) ? tanhfast(acc) : sigf(acc);
            }
            __syncthreads();
            if (tid < 128) {
                float gi = gact[tid], gf = gact[128 + tid], gg = gact[256 + tid], go = gact[384 + tid];
                creg = fmaf(gf, creg, gi * gg);
                hbuf[tid] = go * tanhfast(creg);
            }
            __syncthreads();
            hseg = hbuf[64 * p + lane];
        }
    }

    // ---- (e) classifier MLP on h (track 0), float4-vectorized ----
    if (tid < 64) {
        const float4* W1r = reinterpret_cast<const float4*>(W1 + tid * 128);
        float a = b1[tid];
        #pragma unroll
        for (int q = 0; q < 32; ++q) {
            float4 w = W1r[q];
            a = fmaf(w.x, hbuf[4*q], a);   a = fmaf(w.y, hbuf[4*q+1], a);
            a = fmaf(w.z, hbuf[4*q+2], a); a = fmaf(w.w, hbuf[4*q+3], a);
        }
        mlp1[tid] = fmaxf(a, 0.0f);
    }
    __syncthreads();
    if (tid < 32) {
        const float4* W2r = reinterpret_cast<const float4*>(W2 + tid * 64);
        float a = b2[tid];
        #pragma unroll
        for (int q = 0; q < 16; ++q) {
            float4 w = W2r[q];
            a = fmaf(w.x, mlp1[4*q], a);   a = fmaf(w.y, mlp1[4*q+1], a);
            a = fmaf(w.z, mlp1[4*q+2], a); a = fmaf(w.w, mlp1[4*q+3], a);
        }
        mlp2[tid] = fmaxf(a, 0.0f);
    }
    __syncthreads();
    if (tid == 0) {
        float a = b3[0];
        #pragma unroll
        for (int k = 0; k < 32; ++k) a += W3[k] * mlp2[k];
        out[0] = fmaxf(a, 0.0f);
    }
}

extern "C" void kernel_launch(void* const* d_in, const int* in_sizes, int n_in,
                              void* d_out, int out_size, void* d_ws, size_t ws_size,
                              hipStream_t stream) {
    lstm_disc_kernel<<<1, 1024, 0, stream>>>(
        (const float*)d_in[0],  (const float*)d_in[1],
        (const float*)d_in[2],  (const float*)d_in[3],
        (const float*)d_in[4],  (const float*)d_in[5],
        (const float*)d_in[6],  (const float*)d_in[7],
        (const float*)d_in[8],  (const float*)d_in[9],
        (const float*)d_in[10], (const float*)d_in[11],
        (const float*)d_in[12], (const float*)d_in[13],
        (float*)d_out);
}

// Round 5
// 121.305 us; speedup vs baseline: 1.0473x; 1.0109x over previous
//
#include <hip/hip_runtime.h>
#include <math.h>

#define NT 32768
#define SCALEF 4.0f

// broadcast-readlane: value of v in lane l -> SGPR (wave-uniform), feeds FMA src
__device__ __forceinline__ float rl(float v, int l) {
    return __int_as_float(__builtin_amdgcn_readlane(__float_as_int(v), l));
}

// Pin a loaded value into VGPRs: the asm redefines the components, so the
// backend can neither rematerialize the load inside loops (R2-R4 failure
// mode: VGPR_Count collapsed to 64 and W_hh was re-fetched every step) nor
// fold it back into a memory operand.
__device__ __forceinline__ void pin(float4 &v) {
    asm volatile("" : "+v"(v.x), "+v"(v.y), "+v"(v.z), "+v"(v.w));
}

// fast activations: v_exp_f32 + v_rcp_f32 (~1-2 ulp), monotone & saturating
__device__ __forceinline__ float sigf(float x) {
    return __builtin_amdgcn_rcpf(1.0f + __expf(-x));
}
__device__ __forceinline__ float tanhfast(float x) {
    return 1.0f - 2.0f * __builtin_amdgcn_rcpf(1.0f + __expf(2.0f * x));
}

__device__ __forceinline__ float frame_val(const float* __restrict__ obs,
                                           const float* __restrict__ pred,
                                           int F, int d) {
    return (F < 9) ? obs[F * (NT * 2) + d] : pred[(F - 9) * (NT * 2) + d];
}

// 4 MACs: acc += h[l..l+3] * W.{x,y,z,w}, h broadcast via readlane
#define MAC4(acc, hv, l, W)                       \
    acc = fmaf(rl(hv, (l) + 0), W.x, acc);        \
    acc = fmaf(rl(hv, (l) + 1), W.y, acc);        \
    acc = fmaf(rl(hv, (l) + 2), W.z, acc);        \
    acc = fmaf(rl(hv, (l) + 3), W.w, acc);

// 1024 threads = 16 waves = 4 waves/SIMD -> 128-VGPR budget.
// Thread t: gate j = t&511, half p = t>>9; owns W_hh[j][64p:64p+64) (16 float4)
// and W_ih[j][32p:32p+32) (8 float4): ~116 live regs < 128 => no spill possible.
__launch_bounds__(1024, 4)
__global__ void lstm_disc_kernel(const float* __restrict__ observed,
                                 const float* __restrict__ prediction,
                                 const float* __restrict__ W_emb,
                                 const float* __restrict__ b_emb,
                                 const float* __restrict__ W_ih,
                                 const float* __restrict__ W_hh,
                                 const float* __restrict__ b_ih,
                                 const float* __restrict__ b_hh,
                                 const float* __restrict__ W1,
                                 const float* __restrict__ b1,
                                 const float* __restrict__ W2,
                                 const float* __restrict__ b2,
                                 const float* __restrict__ W3,
                                 const float* __restrict__ b3,
                                 float* __restrict__ out)
{
    const int tid  = (int)threadIdx.x;   // 0..1023
    const int lane = tid & 63;
    const int j    = tid & 511;          // gate index
    const int p    = tid >> 9;           // half index (wave-uniform)

    __shared__ float xs[21][64];         // per-step input embedding vectors
    __shared__ float gxh[2][21 * 512];   // h-independent gate half-partials (+bias in half0)
    __shared__ float ppart[1024];        // per-step dot partials (include gx half)
    __shared__ float hbuf[128];
    __shared__ float velx[21], vely[21], maskf[21];
    __shared__ float mlp1[64];
    __shared__ float mlp2[32];

    // ---- issue weight loads first; C (W_ih) before D (W_hh): vmcnt is ordered,
    // so draining C for the gx phase leaves the D loads in flight underneath it.
    const float4* Wi = reinterpret_cast<const float4*>(W_ih + j * 64 + 32 * p);
    float4 C0 = Wi[0], C1 = Wi[1], C2 = Wi[2], C3 = Wi[3];
    float4 C4 = Wi[4], C5 = Wi[5], C6 = Wi[6], C7 = Wi[7];
    const float4* Wh = reinterpret_cast<const float4*>(W_hh + j * 128 + 64 * p);
    float4 D0  = Wh[0],  D1  = Wh[1],  D2  = Wh[2],  D3  = Wh[3];
    float4 D4  = Wh[4],  D5  = Wh[5],  D6  = Wh[6],  D7  = Wh[7];
    float4 D8  = Wh[8],  D9  = Wh[9],  D10 = Wh[10], D11 = Wh[11];
    float4 D12 = Wh[12], D13 = Wh[13], D14 = Wh[14], D15 = Wh[15];
    const float bias = b_ih[j] + b_hh[j];

    // ---- (a) velocities + visibility masks for track 0 ----
    if (tid < 20) {
        float ax = frame_val(observed, prediction, tid,     0);
        float ay = frame_val(observed, prediction, tid,     1);
        float bx = frame_val(observed, prediction, tid + 1, 0);
        float by = frame_val(observed, prediction, tid + 1, 1);
        unsigned ua = __float_as_uint(ax) & 0x7fffffffu;
        unsigned ub = __float_as_uint(bx) & 0x7fffffffu;
        bool m = !((ua > 0x7f800000u) || (ub > 0x7f800000u));   // NaN-safe
        maskf[tid + 1] = m ? 1.0f : 0.0f;
        velx[tid + 1]  = m ? (bx - ax) * SCALEF : 0.0f;
        vely[tid + 1]  = m ? (by - ay) * SCALEF : 0.0f;
    }
    if (tid == 20) { maskf[0] = 1.0f; velx[0] = 0.0f; vely[0] = 0.0f; }
    __syncthreads();

    // ---- (b) x vectors: xs[1..20] = relu(vel*S @ W_emb^T + b) ++ [0,0]
    for (int idx = tid; idx < 21 * 64; idx += 1024) {
        int s = idx >> 6, e = idx & 63;
        float v;
        if (s == 0)       v = (e == 62) ? 1.0f : 0.0f;   // start tag (handled analytically below)
        else if (e < 62)  v = fmaxf(velx[s] * W_emb[2 * e] + vely[s] * W_emb[2 * e + 1] + b_emb[e], 0.0f);
        else              v = 0.0f;
        xs[s][e] = v;
    }
    __syncthreads();

    // uniform step mask bits
    unsigned mbits = 0;
    #pragma unroll
    for (int s = 0; s < 21; ++s) mbits |= (maskf[s] != 0.0f ? 1u : 0u) << s;

    // ---- pin C into registers (waits C loads only; D stays outstanding) ----
    pin(C0); pin(C1); pin(C2); pin(C3); pin(C4); pin(C5); pin(C6); pin(C7);

    // ---- (c) gx half-partials; own half is folded into the dot later, so the
    // combiner only ever touches ppart. half0 carries the bias.
    float* gmine = &gxh[p][j];
    // s=0: x = one-hot at e=62 (half 1, C7.z since C covers e=32p..32p+31 -> 60..63)
    gmine[0] = (p == 0) ? bias : C7.z;
    const float basev = (p == 0) ? bias : 0.0f;
    float xcs = xs[1][32 * p + (lane & 31)];     // lanes duplicate x[32p..32p+32)
    for (int s = 1; s < 21; ++s) {
        float xcn = (s < 20) ? xs[s + 1][32 * p + (lane & 31)] : 0.0f;
        float a0 = basev, a1 = 0.0f;
        MAC4(a0, xcs,  0, C0) MAC4(a1, xcs,  4, C1)
        MAC4(a0, xcs,  8, C2) MAC4(a1, xcs, 12, C3)
        MAC4(a0, xcs, 16, C4) MAC4(a1, xcs, 20, C5)
        MAC4(a0, xcs, 24, C6) MAC4(a1, xcs, 28, C7)   // x[62..63]==0 for s>=1
        gmine[s * 512] = a0 + a1;
        xcs = xcn;
    }

    // ---- pin D into registers (cannot be rematerialized inside the loop) ----
    pin(D0);  pin(D1);  pin(D2);  pin(D3);  pin(D4);  pin(D5);  pin(D6);  pin(D7);
    pin(D8);  pin(D9);  pin(D10); pin(D11); pin(D12); pin(D13); pin(D14); pin(D15);

    // ---- (d) serial recurrence. No barrier needed before entry: each thread
    // reads only its own gx values; cross-thread data flows through ppart.
    float hseg = 0.0f;                  // h[64p + lane]
    float creg = 0.0f;                  // c[tid], threads tid<128
    for (int s = 0; s < 21; ++s) {
        if (mbits & (1u << s)) {        // uniform branch
            float acc0 = gmine[s * 512];            // ds_read latency hidden by dot
            float acc1 = 0.0f;
            MAC4(acc0, hseg,  0, D0)  MAC4(acc1, hseg,  4, D1)
            MAC4(acc0, hseg,  8, D2)  MAC4(acc1, hseg, 12, D3)
            MAC4(acc0, hseg, 16, D4)  MAC4(acc1, hseg, 20, D5)
            MAC4(acc0, hseg, 24, D6)  MAC4(acc1, hseg, 28, D7)
            MAC4(acc0, hseg, 32, D8)  MAC4(acc1, hseg, 36, D9)
            MAC4(acc0, hseg, 40, D10) MAC4(acc1, hseg, 44, D11)
            MAC4(acc0, hseg, 48, D12) MAC4(acc1, hseg, 52, D13)
            MAC4(acc0, hseg, 56, D14) MAC4(acc1, hseg, 60, D15)
            ppart[tid] = acc0 + acc1;
            __syncthreads();
            if (tid < 128) {            // fused activation + cell update
                float gi = sigf(    ppart[tid]       + ppart[512 + tid]);
                float gf = sigf(    ppart[128 + tid] + ppart[640 + tid]);
                float gg = tanhfast(ppart[256 + tid] + ppart[768 + tid]);
                float go = sigf(    ppart[384 + tid] + ppart[896 + tid]);
                creg = fmaf(gf, creg, gi * gg);
                hbuf[tid] = go * tanhfast(creg);
            }
            __syncthreads();
            hseg = hbuf[64 * p + lane];
        }
    }

    // ---- (e) classifier MLP on h (track 0), float4-vectorized ----
    if (tid < 64) {
        const float4* W1r = reinterpret_cast<const float4*>(W1 + tid * 128);
        float a = b1[tid];
        #pragma unroll
        for (int q = 0; q < 32; ++q) {
            float4 w = W1r[q];
            a = fmaf(w.x, hbuf[4*q], a);   a = fmaf(w.y, hbuf[4*q+1], a);
            a = fmaf(w.z, hbuf[4*q+2], a); a = fmaf(w.w, hbuf[4*q+3], a);
        }
        mlp1[tid] = fmaxf(a, 0.0f);
    }
    __syncthreads();
    if (tid < 32) {
        const float4* W2r = reinterpret_cast<const float4*>(W2 + tid * 64);
        float a = b2[tid];
        #pragma unroll
        for (int q = 0; q < 16; ++q) {
            float4 w = W2r[q];
            a = fmaf(w.x, mlp1[4*q], a);   a = fmaf(w.y, mlp1[4*q+1], a);
            a = fmaf(w.z, mlp1[4*q+2], a); a = fmaf(w.w, mlp1[4*q+3], a);
        }
        mlp2[tid] = fmaxf(a, 0.0f);
    }
    __syncthreads();
    if (tid == 0) {
        float a = b3[0];
        #pragma unroll
        for (int k = 0; k < 32; ++k) a += W3[k] * mlp2[k];
        out[0] = fmaxf(a, 0.0f);
    }
}

extern "C" void kernel_launch(void* const* d_in, const int* in_sizes, int n_in,
                              void* d_out, int out_size, void* d_ws, size_t ws_size,
                              hipStream_t stream) {
    lstm_disc_kernel<<<1, 1024, 0, stream>>>(
        (const float*)d_in[0],  (const float*)d_in[1],
        (const float*)d_in[2],  (const float*)d_in[3],
        (const float*)d_in[4],  (const float*)d_in[5],
        (const float*)d_in[6],  (const float*)d_in[7],
        (const float*)d_in[8],  (const float*)d_in[9],
        (const float*)d_in[10], (const float*)d_in[11],
        (const float*)d_in[12], (const float*)d_in[13],
        (float*)d_out);
}

// Round 6
// 113.522 us; speedup vs baseline: 1.1191x; 1.0686x over previous
//
#include <hip/hip_runtime.h>
#include <math.h>

#define NT 32768
#define SCALEF 4.0f

typedef _Float16 h2v __attribute__((ext_vector_type(2)));

// broadcast-readlane (uint / float)
__device__ __forceinline__ unsigned rlu(unsigned u, int l) {
    return (unsigned)__builtin_amdgcn_readlane((int)u, l);
}

// pack two fp32 into f16x2 (RNE via _Float16 cast)
__device__ __forceinline__ unsigned pk2(float lo, float hi) {
    unsigned a = (unsigned)__builtin_bit_cast(unsigned short, (_Float16)lo);
    unsigned b = (unsigned)__builtin_bit_cast(unsigned short, (_Float16)hi);
    return a | (b << 16);
}
__device__ __forceinline__ float upk_lo(unsigned u) {
    return (float)__builtin_bit_cast(_Float16, (unsigned short)(u & 0xffffu));
}
__device__ __forceinline__ float upk_hi(unsigned u) {
    return (float)__builtin_bit_cast(_Float16, (unsigned short)(u >> 16));
}

// 2 MACs: acc += w.f16x2 . h.f16x2  (v_dot2_f32_f16, fp32 accumulate)
__device__ __forceinline__ float dot2(unsigned w, unsigned h, float acc) {
#if defined(__has_builtin) && __has_builtin(__builtin_amdgcn_fdot2)
    return __builtin_amdgcn_fdot2(__builtin_bit_cast(h2v, w),
                                  __builtin_bit_cast(h2v, h), acc, false);
#else
    acc = fmaf(upk_lo(w), upk_lo(h), acc);
    return fmaf(upk_hi(w), upk_hi(h), acc);
#endif
}

// fast activations: v_exp_f32 + v_rcp_f32
__device__ __forceinline__ float sigf(float x) {
    return __builtin_amdgcn_rcpf(1.0f + __expf(-x));
}
__device__ __forceinline__ float tanhfast(float x) {
    return 1.0f - 2.0f * __builtin_amdgcn_rcpf(1.0f + __expf(2.0f * x));
}

__device__ __forceinline__ float frame_val(const float* __restrict__ obs,
                                           const float* __restrict__ pred,
                                           int F, int d) {
    return (F < 9) ? obs[F * (NT * 2) + d] : pred[(F - 9) * (NT * 2) + d];
}

// 1024 threads = 16 waves. Thread t: gate j = t&511, half p = t>>9.
// W_hh lives in LDS as f16 pairs (131 KB), XOR-swizzled 16-B granules so each
// wave's 8 ds_read_b128 hit all 8 bank-quads (conflict-free). W_ih half-row =
// 16 f16x2 uints, pinned in registers (small enough to survive 64-reg budget).
__launch_bounds__(1024, 4)
__global__ void lstm_disc_kernel(const float* __restrict__ observed,
                                 const float* __restrict__ prediction,
                                 const float* __restrict__ W_emb,
                                 const float* __restrict__ b_emb,
                                 const float* __restrict__ W_ih,
                                 const float* __restrict__ W_hh,
                                 const float* __restrict__ b_ih,
                                 const float* __restrict__ b_hh,
                                 const float* __restrict__ W1,
                                 const float* __restrict__ b1,
                                 const float* __restrict__ W2,
                                 const float* __restrict__ b2,
                                 const float* __restrict__ W3,
                                 const float* __restrict__ b3,
                                 float* __restrict__ out)
{
    const int tid  = (int)threadIdx.x;   // 0..1023
    const int lane = tid & 63;
    const int j    = tid & 511;          // gate index
    const int p    = tid >> 9;           // half index (wave-uniform)
    const int s7   = tid & 7;            // XOR-swizzle key
    const int gbase = tid * 8;           // granule base in whh4

    __shared__ uint4    whh4[1024 * 8];  // 131072 B: f16x2 W_hh, swizzled
    __shared__ unsigned xs_pk[21 * 32];  // 2688 B: f16x2 input vectors
    __shared__ float    ppart[1024];     // per-step dot partials
    __shared__ unsigned hpk[64];         // h as f16 pairs
    __shared__ float    hfin[128];       // fp32 h (for MLP tail)
    __shared__ float    velx[21], vely[21], maskf[21];
    __shared__ float    mlp1[64], mlp2[32];

    // ---- (a) velocities + visibility masks for track 0 ----
    if (tid < 20) {
        float ax = frame_val(observed, prediction, tid,     0);
        float ay = frame_val(observed, prediction, tid,     1);
        float bx = frame_val(observed, prediction, tid + 1, 0);
        float by = frame_val(observed, prediction, tid + 1, 1);
        unsigned ua = __float_as_uint(ax) & 0x7fffffffu;
        unsigned ub = __float_as_uint(bx) & 0x7fffffffu;
        bool m = !((ua > 0x7f800000u) || (ub > 0x7f800000u));   // NaN-safe
        maskf[tid + 1] = m ? 1.0f : 0.0f;
        velx[tid + 1]  = m ? (bx - ax) * SCALEF : 0.0f;
        vely[tid + 1]  = m ? (by - ay) * SCALEF : 0.0f;
    }
    if (tid == 20) { maskf[0] = 1.0f; velx[0] = 0.0f; vely[0] = 0.0f; }

    // ---- W_ih half-row -> 16 pinned f16x2 regs (issue loads early) ----
    unsigned xw[16];
    {
        const float4* Wi = reinterpret_cast<const float4*>(W_ih + j * 64 + 32 * p);
        #pragma unroll
        for (int q = 0; q < 8; ++q) {
            float4 w = Wi[q];
            xw[2 * q]     = pk2(w.x, w.y);
            xw[2 * q + 1] = pk2(w.z, w.w);
        }
        #pragma unroll
        for (int q = 0; q < 16; ++q) asm volatile("" : "+v"(xw[q]));
    }
    const float bias = b_ih[j] + b_hh[j];

    __syncthreads();    // velx/maskf ready

    // ---- (b) x vectors, packed f16: xs[0]=one-hot@62, xs[1..20]=relu(vel@W^T+b)++[0,0]
    unsigned short* xs16 = (unsigned short*)xs_pk;
    for (int idx = tid; idx < 21 * 64; idx += 1024) {
        int s = idx >> 6, e = idx & 63;
        float v;
        if (s == 0)      v = (e == 62) ? 1.0f : 0.0f;
        else if (e < 62) v = fmaxf(velx[s] * W_emb[2 * e] + vely[s] * W_emb[2 * e + 1] + b_emb[e], 0.0f);
        else             v = 0.0f;
        xs16[s * 64 + e] = __builtin_bit_cast(unsigned short, (_Float16)v);
    }

    // ---- (c) stage W_hh half-row into LDS as f16 pairs, swizzled granules ----
    {
        const float4* Wh = reinterpret_cast<const float4*>(W_hh + j * 128 + 64 * p);
        #pragma unroll
        for (int g = 0; g < 8; ++g) {
            float4 wa = Wh[2 * g], wb = Wh[2 * g + 1];
            uint4 u;
            u.x = pk2(wa.x, wa.y); u.y = pk2(wa.z, wa.w);
            u.z = pk2(wb.x, wb.y); u.w = pk2(wb.z, wb.w);
            whh4[gbase + (g ^ s7)] = u;
        }
    }

    // uniform step mask bits
    unsigned mbits = 0;
    #pragma unroll
    for (int s = 0; s < 21; ++s) mbits |= (maskf[s] != 0.0f ? 1u : 0u) << s;

    __syncthreads();    // xs_pk + whh4 ready

    // ---- (d) serial recurrence: W_hh from LDS (f16x2), h broadcast as f16
    // pairs via readlane, fp32 accumulate; c stays fp32 in combiner regs.
    unsigned short* hpk16 = (unsigned short*)hpk;
    float creg = 0.0f;
    unsigned hp = 0u;                    // packed h pair (32p + lane&31); f16 zeros
    for (int s = 0; s < 21; ++s) {
        if (mbits & (1u << s)) {         // uniform branch
            unsigned xp = xs_pk[s * 32 + 16 * p + (lane & 15)];
            uint4 wA = whh4[gbase + (0 ^ s7)];
            uint4 wB = whh4[gbase + (1 ^ s7)];
            float a0 = (p == 0) ? bias : 0.0f;
            float a1 = 0.0f;
            #pragma unroll
            for (int g = 0; g < 8; ++g) {           // h-dot: 64 MACs
                uint4 wc = (g & 1) ? wB : wA;
                if (g + 2 < 8) {
                    uint4 wn = whh4[gbase + ((g + 2) ^ s7)];
                    if (g & 1) wB = wn; else wA = wn;
                }
                a0 = dot2(wc.x, rlu(hp, 4 * g + 0), a0);
                a1 = dot2(wc.y, rlu(hp, 4 * g + 1), a1);
                a0 = dot2(wc.z, rlu(hp, 4 * g + 2), a0);
                a1 = dot2(wc.w, rlu(hp, 4 * g + 3), a1);
            }
            #pragma unroll
            for (int q = 0; q < 16; ++q) {          // x-dot: 32 MACs (reg weights)
                if (q & 1) a1 = dot2(xw[q], rlu(xp, q), a1);
                else       a0 = dot2(xw[q], rlu(xp, q), a0);
            }
            ppart[tid] = a0 + a1;
            __syncthreads();
            if (tid < 128) {             // fused activation + cell update
                float gi = sigf(    ppart[tid      ] + ppart[512 + tid]);
                float gf = sigf(    ppart[128 + tid] + ppart[640 + tid]);
                float gg = tanhfast(ppart[256 + tid] + ppart[768 + tid]);
                float go = sigf(    ppart[384 + tid] + ppart[896 + tid]);
                creg = fmaf(gf, creg, gi * gg);
                float hv = go * tanhfast(creg);
                hfin[tid] = hv;
                hpk16[tid] = __builtin_bit_cast(unsigned short, (_Float16)hv);
            }
            __syncthreads();
            hp = hpk[32 * p + (lane & 31)];
        }
    }

    // ---- (e) classifier MLP on h (track 0), fp32 h, float4 weights ----
    if (tid < 64) {
        const float4* W1r = reinterpret_cast<const float4*>(W1 + tid * 128);
        float a = b1[tid];
        #pragma unroll
        for (int q = 0; q < 32; ++q) {
            float4 w = W1r[q];
            a = fmaf(w.x, hfin[4*q], a);   a = fmaf(w.y, hfin[4*q+1], a);
            a = fmaf(w.z, hfin[4*q+2], a); a = fmaf(w.w, hfin[4*q+3], a);
        }
        mlp1[tid] = fmaxf(a, 0.0f);
    }
    __syncthreads();
    if (tid < 32) {
        const float4* W2r = reinterpret_cast<const float4*>(W2 + tid * 64);
        float a = b2[tid];
        #pragma unroll
        for (int q = 0; q < 16; ++q) {
            float4 w = W2r[q];
            a = fmaf(w.x, mlp1[4*q], a);   a = fmaf(w.y, mlp1[4*q+1], a);
            a = fmaf(w.z, mlp1[4*q+2], a); a = fmaf(w.w, mlp1[4*q+3], a);
        }
        mlp2[tid] = fmaxf(a, 0.0f);
    }
    __syncthreads();
    if (tid == 0) {
        float a = b3[0];
        #pragma unroll
        for (int k = 0; k < 32; ++k) a += W3[k] * mlp2[k];
        out[0] = fmaxf(a, 0.0f);
    }
}

extern "C" void kernel_launch(void* const* d_in, const int* in_sizes, int n_in,
                              void* d_out, int out_size, void* d_ws, size_t ws_size,
                              hipStream_t stream) {
    lstm_disc_kernel<<<1, 1024, 0, stream>>>(
        (const float*)d_in[0],  (const float*)d_in[1],
        (const float*)d_in[2],  (const float*)d_in[3],
        (const float*)d_in[4],  (const float*)d_in[5],
        (const float*)d_in[6],  (const float*)d_in[7],
        (const float*)d_in[8],  (const float*)d_in[9],
        (const float*)d_in[10], (const float*)d_in[11],
        (const float*)d_in[12], (const float*)d_in[13],
        (float*)d_out);
}